// Round 10
// baseline (133.601 us; speedup 1.0000x reference)
//
#include <hip/hip_runtime.h>
#include <stdint.h>

#define DDIM 1024
#define HH 16
#define HDIM 64
#define SS 2048

typedef short bf16x8 __attribute__((ext_vector_type(8)));
typedef float f32x4 __attribute__((ext_vector_type(4)));
typedef float f32x16 __attribute__((ext_vector_type(16)));
typedef unsigned short u16;

__device__ __forceinline__ unsigned f2bf(float f) {
  unsigned u = __builtin_bit_cast(unsigned, f);
  u = u + 0x7FFFu + ((u >> 16) & 1u);   // RNE (inputs finite)
  return u >> 16;
}

// packs RNE-converted a->lo16, b->hi16
__device__ __forceinline__ unsigned cvt_pk_bf16(float a, float b) {
  unsigned r;
  asm("v_cvt_pk_bf16_f32 %0, %1, %2" : "=v"(r) : "v"(a), "v"(b));
  return r;
}

// after: a = [a.l0_31 | b.l0_31], b = [a.l32_63 | b.l32_63]
__device__ __forceinline__ void pswap(unsigned& a, unsigned& b) {
  asm volatile("v_permlane32_swap_b32 %0, %1" : "+v"(a), "+v"(b));
}

__device__ __forceinline__ void gload16(const void* g, void* l) {
  __builtin_amdgcn_global_load_lds(
      (const __attribute__((address_space(1))) unsigned int*)g,
      (__attribute__((address_space(3))) unsigned int*)l, 16, 0, 0);
}

__device__ __forceinline__ f32x16 zero16() {
  f32x16 z;
#pragma unroll
  for (int r = 0; r < 16; r++) z[r] = 0.f;
  return z;
}

// ---------------- convert x: fp32 -> bf16 ----------------
__global__ void k_convert_x(const float* __restrict__ x, u16* __restrict__ xb) {
  int i = (blockIdx.x * 256 + threadIdx.x) * 4;
  float4 v = *(const float4*)(x + i);
  ushort4 o;
  o.x = (u16)f2bf(v.x); o.y = (u16)f2bf(v.y); o.z = (u16)f2bf(v.z); o.w = (u16)f2bf(v.w);
  *(ushort4*)(xb + i) = o;
}

// ---------------- transpose+convert weights: W[k][n] -> WT[n][k] bf16 ----------------
__global__ void k_transpose_w(const float* __restrict__ w0, const float* __restrict__ w1,
                              const float* __restrict__ w2, const float* __restrict__ w3,
                              u16* __restrict__ wt) {
  __shared__ float t[64][65];
  int z = blockIdx.z;
  const float* src = (z == 0) ? w0 : (z == 1) ? w1 : (z == 2) ? w2 : w3;
  u16* dst = wt + (size_t)z * DDIM * DDIM;
  int k0 = blockIdx.x * 64, n0 = blockIdx.y * 64;
  int tid = threadIdx.x;
  int c4 = tid & 15, rr = tid >> 4;
  for (int rep = 0; rep < 4; rep++) {
    int r = rr + rep * 16;
    float4 v = *(const float4*)(src + (size_t)(k0 + r) * DDIM + n0 + c4 * 4);
    t[r][c4 * 4 + 0] = v.x; t[r][c4 * 4 + 1] = v.y;
    t[r][c4 * 4 + 2] = v.z; t[r][c4 * 4 + 3] = v.w;
  }
  __syncthreads();
  for (int rep = 0; rep < 4; rep++) {
    int n = rr + rep * 16;
    ushort4 o;
    o.x = (u16)f2bf(t[c4 * 4 + 0][n]); o.y = (u16)f2bf(t[c4 * 4 + 1][n]);
    o.z = (u16)f2bf(t[c4 * 4 + 2][n]); o.w = (u16)f2bf(t[c4 * 4 + 3][n]);
    *(ushort4*)(dst + (size_t)(n0 + n) * DDIM + k0 + c4 * 4) = o;
  }
}

// ---------------- GEMM: tile 128x128, BK=64, K=1024; A[m][k], BT[n][k] bf16 ----------------
template <int MODE>
__global__ __launch_bounds__(256, 2) void k_gemm(const u16* __restrict__ A,
                                                 const u16* __restrict__ BT,
                                                 const float* __restrict__ bias,
                                                 void* __restrict__ O0,
                                                 void* __restrict__ O1,
                                                 void* __restrict__ O2) {
  __shared__ __align__(16) u16 lA[128 * 64];
  __shared__ __align__(16) u16 lB[128 * 64];
  const int tid = threadIdx.x;
  const int l = tid & 63, w = tid >> 6;
  const int wm = w >> 1, wn = w & 1;
  const int m0 = blockIdx.x * 128, n0 = blockIdx.y * 128;
  const int lr = l >> 4, lc = l & 15;

  const int srow = l >> 3;
  const int scol = ((l & 7) ^ srow) * 8;

  f32x4 acc[4][4];
  for (int mi = 0; mi < 4; mi++)
    for (int ni = 0; ni < 4; ni++)
      acc[mi][ni] = f32x4{0.f, 0.f, 0.f, 0.f};

  for (int kk = 0; kk < 16; kk++) {
    const int k0 = kk * 64;
    for (int i = 0; i < 4; i++) {
      int c = w * 4 + i;
      gload16(A + (size_t)(m0 + c * 8 + srow) * DDIM + k0 + scol, (char*)lA + c * 1024);
      gload16(BT + (size_t)(n0 + c * 8 + srow) * DDIM + k0 + scol, (char*)lB + c * 1024);
    }
    __syncthreads();
    for (int ks = 0; ks < 2; ks++) {
      bf16x8 af[4], bfr[4];
      for (int mi = 0; mi < 4; mi++) {
        int row = wm * 64 + mi * 16 + lc;
        int slot = (ks * 4 + lr) ^ (row & 7);
        af[mi] = *(const bf16x8*)((const char*)lA + row * 128 + slot * 16);
      }
      for (int ni = 0; ni < 4; ni++) {
        int row = wn * 64 + ni * 16 + lc;
        int slot = (ks * 4 + lr) ^ (row & 7);
        bfr[ni] = *(const bf16x8*)((const char*)lB + row * 128 + slot * 16);
      }
      for (int mi = 0; mi < 4; mi++)
        for (int ni = 0; ni < 4; ni++)
          acc[mi][ni] = __builtin_amdgcn_mfma_f32_16x16x32_bf16(af[mi], bfr[ni], acc[mi][ni], 0, 0, 0);
    }
    __syncthreads();
  }

  if (MODE == 0) {
    const int which = blockIdx.y >> 3;
    if (which == 0) {
      u16* C = (u16*)O0;
      const float c1 = 0.18033688011112043f;  // 0.125 * log2(e) folded into Q
      for (int mi = 0; mi < 4; mi++)
        for (int ni = 0; ni < 4; ni++) {
          int nl = (n0 + wn * 64 + ni * 16 + lc) & 1023;
          float badd = bias[nl];
          for (int r = 0; r < 4; r++) {
            int m = m0 + wm * 64 + mi * 16 + lr * 4 + r;
            C[(size_t)m * DDIM + nl] = (u16)f2bf((acc[mi][ni][r] + badd) * c1);
          }
        }
    } else if (which == 1) {
      u16* C = (u16*)O1;
      for (int mi = 0; mi < 4; mi++)
        for (int ni = 0; ni < 4; ni++) {
          int nl = (n0 + wn * 64 + ni * 16 + lc) & 1023;
          for (int r = 0; r < 4; r++) {
            int m = m0 + wm * 64 + mi * 16 + lr * 4 + r;
            C[(size_t)m * DDIM + nl] = (u16)f2bf(acc[mi][ni][r]);
          }
        }
    } else {
      u16* C = (u16*)O2;  // [bh][hd][s]
      for (int mi = 0; mi < 4; mi++)
        for (int ni = 0; ni < 4; ni++) {
          int nl = (n0 + wn * 64 + ni * 16 + lc) & 1023;
          int h = nl >> 6, hd = nl & 63;
          int m = m0 + wm * 64 + mi * 16 + lr * 4;
          int b = m >> 11, s = m & 2047;
          unsigned d0 = f2bf(acc[mi][ni][0]) | (f2bf(acc[mi][ni][1]) << 16);
          unsigned d1 = f2bf(acc[mi][ni][2]) | (f2bf(acc[mi][ni][3]) << 16);
          u16* p = C + ((size_t)((b * HH + h) * HDIM + hd)) * SS + s;
          *(unsigned*)(p) = d0;
          *(unsigned*)(p + 2) = d1;
        }
    }
  } else {
    float* C = (float*)O0;
    for (int mi = 0; mi < 4; mi++)
      for (int ni = 0; ni < 4; ni++) {
        int n = n0 + wn * 64 + ni * 16 + lc;
        float badd = bias[n];
        for (int r = 0; r < 4; r++) {
          int m = m0 + wm * 64 + mi * 16 + lr * 4 + r;
          C[(size_t)m * DDIM + n] = acc[mi][ni][r] + badd;
        }
      }
  }
}

// ---------------- flash attention: 32x32 MFMA, in-register softmax (no P LDS) ----------
// Wave owns 32 q (col=lane&31). S^T = mfma_32x32x16(K, Q): lane holds 16 keys (+partner 16).
// Softmax: in-lane tree + ONE shfl_xor(32). P -> bf16 B-frags via cvt_pk + permlane32_swap.
// Block = 4 waves = strips {4g..4g+3}; counted vmcnt(4) ring; KVBLK=64; LDS 32 KB.
__global__ __launch_bounds__(256, 2) void k_attn(const u16* __restrict__ Q,
                                                 const u16* __restrict__ Kg,
                                                 const u16* __restrict__ Vt,
                                                 u16* __restrict__ AO) {
  __shared__ __align__(16) u16 lK[2][64 * 64];  // [key][d] XOR-swizzled, dbuf (16 KB)
  __shared__ __align__(16) u16 lV[2][64 * 64];  // [hd][key] XOR-swizzled, dbuf (16 KB)

  const int tid = threadIdx.x;
  const int l = tid & 63, w = tid >> 6;
  const int lq = l & 31, hi = l >> 5;
  const int id = blockIdx.x;
  const int bh = id & 31;                       // id%8 = bh%8 -> XCD affinity (R5-proven)
  const int gslot = id >> 5;                    // 0..15
  const int g = (gslot < 8) ? gslot : 23 - gslot;  // CU pairs (g, 15-g): 34 periods total
  const int b = bh >> 4, h = bh & 15;
  const int sw = g * 4 + w;                     // wave's 32-q strip, 0..63
  const int qglob = sw * 32 + lq;
  const int nktw = (sw >> 1) + 1;               // this wave's active periods
  const int nkt = 2 * g + 2;                    // block periods

  const float slope2 = exp2f(-0.5f * (float)(h + 1)) * 1.4426950408889634f;
  const float sh4 = slope2 * (float)(4 * hi);

  // per-reg ALiBi constants: scr[r] = slope2 * crow(r) (crow = (r&3)+8*(r>>2))
  f32x16 scr;
#pragma unroll
  for (int r = 0; r < 16; r++) scr[r] = slope2 * (float)((r & 3) + 8 * (r >> 2));

  // Q B-frags: col q = lq, k(d) = sd*16 + hi*8 + j
  bf16x8 qf[4];
#pragma unroll
  for (int sd = 0; sd < 4; sd++)
    qf[sd] = *(const bf16x8*)(Q + (size_t)(b * SS + qglob) * DDIM + h * HDIM + sd * 16 + hi * 8);

  f32x16 o0 = zero16(), o1 = zero16();
  float mrun = -3.0e38f, lrl = 0.f;

  const int srow = l >> 3;
  const int scol = ((l & 7) ^ srow) * 8;

  auto stage = [&](int kt, int bb) {
#pragma unroll
    for (int i = 0; i < 2; i++) {
      int c = i * 4 + w;   // 8 chunks of 8 rows x 64 cols (1 KB)
      gload16(Kg + (size_t)(b * SS + kt * 64 + c * 8 + srow) * DDIM + h * HDIM + scol,
              (char*)lK[bb] + c * 1024);
      gload16(Vt + ((size_t)bh * HDIM + c * 8 + srow) * SS + kt * 64 + scol,
              (char*)lV[bb] + c * 1024);
    }
  };

  // prologue: two tiles in flight (nkt >= 2 always)
  stage(0, 0);
  stage(1, 1);

  for (int t = 0; t < nkt; t++) {
    asm volatile("s_waitcnt vmcnt(4)" ::: "memory");
    __builtin_amdgcn_s_barrier();
    asm volatile("" ::: "memory");
    if (t < nktw) {
      const char* Kc = (const char*)lK[t & 1];
      const char* Vc = (const char*)lV[t & 1];
      const bool lastp = (t == nktw - 1);
      const bool doT1 = !lastp || (sw & 1);     // even strip's last period: skip key-tile 1
      const bool mT0 = lastp && !(sw & 1);
      const bool mT1 = lastp && (sw & 1);

      // S^T[key][q] = K . Q^T  (2 key-tiles x 4 d-steps)
      f32x16 s0 = zero16(), s1 = zero16();
      __builtin_amdgcn_s_setprio(1);
#pragma unroll
      for (int sd = 0; sd < 4; sd++) {
        int row = lq;
        int slot = (2 * sd + hi) ^ (row & 7);
        bf16x8 a = *(const bf16x8*)(Kc + row * 128 + slot * 16);
        s0 = __builtin_amdgcn_mfma_f32_32x32x16_bf16(a, qf[sd], s0, 0, 0, 0);
      }
      if (doT1) {
#pragma unroll
        for (int sd = 0; sd < 4; sd++) {
          int row = 32 + lq;
          int slot = (2 * sd + hi) ^ (row & 7);
          bf16x8 a = *(const bf16x8*)(Kc + row * 128 + slot * 16);
          s1 = __builtin_amdgcn_mfma_f32_32x32x16_bf16(a, qf[sd], s1, 0, 0, 0);
        }
      }
      __builtin_amdgcn_s_setprio(0);

      // ALiBi (exp2 domain) + causal mask + per-lane max over held keys
      const float bt0 = -slope2 * (float)(t * 64) - sh4;
      const float bt1 = bt0 - slope2 * 32.f;
      float tmax = -3.0e38f;
#pragma unroll
      for (int r = 0; r < 16; r++) {
        float sv = (s0[r] + bt0) - scr[r];
        if (mT0) {
          int key = t * 64 + (r & 3) + 8 * (r >> 2) + 4 * hi;
          if (key > qglob) sv = -3.0e38f;
        }
        s0[r] = sv;
        tmax = fmaxf(tmax, sv);
      }
      if (doT1) {
#pragma unroll
        for (int r = 0; r < 16; r++) {
          float sv = (s1[r] + bt1) - scr[r];
          if (mT1) {
            int key = t * 64 + 32 + (r & 3) + 8 * (r >> 2) + 4 * hi;
            if (key > qglob) sv = -3.0e38f;
          }
          s1[r] = sv;
          tmax = fmaxf(tmax, sv);
        }
      }
      // column max: in-lane tree already done; ONE cross-lane exchange (partner half)
      float tcol = fmaxf(tmax, __shfl_xor(tmax, 32));
      if (__any(tcol > mrun)) {
        float mnew = fmaxf(mrun, tcol);
        float corr = exp2f(mrun - mnew);
        lrl *= corr;
#pragma unroll
        for (int r = 0; r < 16; r++) { o0[r] *= corr; o1[r] *= corr; }
        mrun = mnew;
      }

      // p = exp2(sv - m): per-lane partial denominator (combined once at epilogue)
      f32x4 ps = f32x4{0.f, 0.f, 0.f, 0.f};
#pragma unroll
      for (int r = 0; r < 16; r++) {
        float p = exp2f(s0[r] - mrun);
        s0[r] = p;
        ps[r & 3] += p;
      }
      if (doT1) {
#pragma unroll
        for (int r = 0; r < 16; r++) {
          float p = exp2f(s1[r] - mrun);
          s1[r] = p;
          ps[r & 3] += p;
        }
      }
      lrl += (ps[0] + ps[1]) + (ps[2] + ps[3]);

      // O^T[hd][q] += V^T . P : P -> B-frags in-register (cvt_pk + permlane32_swap)
      __builtin_amdgcn_s_setprio(1);
      auto pvstep = [&](const f32x16& cs, int s) {  // s = 16-key step 0..3 (unroll const)
        const int b8 = (s & 1) * 8;
        unsigned x1 = cvt_pk_bf16(cs[b8 + 0], cs[b8 + 1]);
        unsigned y1 = cvt_pk_bf16(cs[b8 + 4], cs[b8 + 5]);
        pswap(x1, y1);   // x1 -> keys (0,1)+8hi; y1 -> keys (4,5)+8hi
        unsigned x2 = cvt_pk_bf16(cs[b8 + 2], cs[b8 + 3]);
        unsigned y2 = cvt_pk_bf16(cs[b8 + 6], cs[b8 + 7]);
        pswap(x2, y2);   // x2 -> keys (2,3)+8hi; y2 -> keys (6,7)+8hi
        uint4 pw; pw.x = x1; pw.y = x2; pw.z = y1; pw.w = y2;
        bf16x8 pb = __builtin_bit_cast(bf16x8, pw);
        int slotb = 2 * s + hi;
        {
          int row = lq;
          bf16x8 va = *(const bf16x8*)(Vc + row * 128 + ((slotb ^ (row & 7)) << 4));
          o0 = __builtin_amdgcn_mfma_f32_32x32x16_bf16(va, pb, o0, 0, 0, 0);
        }
        {
          int row = 32 + lq;
          bf16x8 va = *(const bf16x8*)(Vc + row * 128 + ((slotb ^ (row & 7)) << 4));
          o1 = __builtin_amdgcn_mfma_f32_32x32x16_bf16(va, pb, o1, 0, 0, 0);
        }
      };
      pvstep(s0, 0);
      pvstep(s0, 1);
      if (doT1) {
        pvstep(s1, 2);
        pvstep(s1, 3);
      }
      __builtin_amdgcn_s_setprio(0);
    }
    __builtin_amdgcn_s_barrier();
    asm volatile("" ::: "memory");
    int kts = t + 2;
    if (kts > nkt - 1) kts = nkt - 1;   // redundant stage keeps vmcnt counts uniform
    stage(kts, t & 1);
  }

  // epilogue: combine per-lane denominator with partner half; normalize; write O
  float lcol = lrl + __shfl_xor(lrl, 32);
  float inv = 1.f / lcol;
  u16* obase = AO + (size_t)(b * SS + qglob) * DDIM + h * HDIM;
#pragma unroll
  for (int rg = 0; rg < 4; rg++) {
    uint2 uu;
    uu.x = cvt_pk_bf16(o0[4 * rg + 0] * inv, o0[4 * rg + 1] * inv);
    uu.y = cvt_pk_bf16(o0[4 * rg + 2] * inv, o0[4 * rg + 3] * inv);
    *(uint2*)(obase + rg * 8 + 4 * hi) = uu;
    uu.x = cvt_pk_bf16(o1[4 * rg + 0] * inv, o1[4 * rg + 1] * inv);
    uu.y = cvt_pk_bf16(o1[4 * rg + 2] * inv, o1[4 * rg + 3] * inv);
    *(uint2*)(obase + 32 + rg * 8 + 4 * hi) = uu;
  }
}

extern "C" void kernel_launch(void* const* d_in, const int* in_sizes, int n_in,
                              void* d_out, int out_size, void* d_ws, size_t ws_size,
                              hipStream_t stream) {
  const float* x  = (const float*)d_in[0];
  const float* Wq = (const float*)d_in[1];
  const float* bq = (const float*)d_in[2];
  const float* Wk = (const float*)d_in[3];
  const float* Wv = (const float*)d_in[4];
  const float* Wo = (const float*)d_in[5];
  const float* bo = (const float*)d_in[6];
  float* out = (float*)d_out;

  u16* ws = (u16*)d_ws;
  const size_t MEG = 1024 * 1024;
  u16* xb = ws;                  // 4M elems
  u16* WT = ws + 4 * MEG;        // 4 x 1M elems: WqT,WkT,WvT,WoT
  u16* Qb = ws + 8 * MEG;        // 4M
  u16* Kb = ws + 12 * MEG;       // 4M
  u16* Vt = ws + 16 * MEG;       // 4M  [32][64][2048]
  u16* AO = ws + 20 * MEG;       // 4M

  k_convert_x<<<dim3(4096), dim3(256), 0, stream>>>(x, xb);
  k_transpose_w<<<dim3(16, 16, 4), dim3(256), 0, stream>>>(Wq, Wk, Wv, Wo, WT);
  k_gemm<0><<<dim3(32, 24), dim3(256), 0, stream>>>(xb, WT, bq, (void*)Qb, (void*)Kb, (void*)Vt);
  k_attn<<<dim3(512), dim3(256), 0, stream>>>(Qb, Kb, Vt, AO);
  k_gemm<1><<<dim3(32, 8), dim3(256), 0, stream>>>(AO, WT + 3 * MEG, bo, (void*)out, nullptr, nullptr);
}

// Round 11
// 133.296 us; speedup vs baseline: 1.0023x; 1.0023x over previous
//
#include <hip/hip_runtime.h>
#include <stdint.h>

#define DDIM 1024
#define HH 16
#define HDIM 64
#define SS 2048

typedef short bf16x8 __attribute__((ext_vector_type(8)));
typedef float f32x4 __attribute__((ext_vector_type(4)));
typedef float f32x16 __attribute__((ext_vector_type(16)));
typedef unsigned short u16;

__device__ __forceinline__ unsigned f2bf(float f) {
  unsigned u = __builtin_bit_cast(unsigned, f);
  u = u + 0x7FFFu + ((u >> 16) & 1u);   // RNE (inputs finite)
  return u >> 16;
}

// packs RNE-converted a->lo16, b->hi16
__device__ __forceinline__ unsigned cvt_pk_bf16(float a, float b) {
  unsigned r;
  asm("v_cvt_pk_bf16_f32 %0, %1, %2" : "=v"(r) : "v"(a), "v"(b));
  return r;
}

// after: a = [a.l0_31 | b.l0_31], b = [a.l32_63 | b.l32_63]
__device__ __forceinline__ void pswap(unsigned& a, unsigned& b) {
  asm volatile("v_permlane32_swap_b32 %0, %1" : "+v"(a), "+v"(b));
}

__device__ __forceinline__ void gload16(const void* g, void* l) {
  __builtin_amdgcn_global_load_lds(
      (const __attribute__((address_space(1))) unsigned int*)g,
      (__attribute__((address_space(3))) unsigned int*)l, 16, 0, 0);
}

__device__ __forceinline__ f32x16 zero16() {
  f32x16 z;
#pragma unroll
  for (int r = 0; r < 16; r++) z[r] = 0.f;
  return z;
}

// ---------------- convert x: fp32 -> bf16 ----------------
__global__ void k_convert_x(const float* __restrict__ x, u16* __restrict__ xb) {
  int i = (blockIdx.x * 256 + threadIdx.x) * 4;
  float4 v = *(const float4*)(x + i);
  ushort4 o;
  o.x = (u16)f2bf(v.x); o.y = (u16)f2bf(v.y); o.z = (u16)f2bf(v.z); o.w = (u16)f2bf(v.w);
  *(ushort4*)(xb + i) = o;
}

// ---------------- transpose+convert weights: W[k][n] -> WT[n][k] bf16 ----------------
__global__ void k_transpose_w(const float* __restrict__ w0, const float* __restrict__ w1,
                              const float* __restrict__ w2, const float* __restrict__ w3,
                              u16* __restrict__ wt) {
  __shared__ float t[64][65];
  int z = blockIdx.z;
  const float* src = (z == 0) ? w0 : (z == 1) ? w1 : (z == 2) ? w2 : w3;
  u16* dst = wt + (size_t)z * DDIM * DDIM;
  int k0 = blockIdx.x * 64, n0 = blockIdx.y * 64;
  int tid = threadIdx.x;
  int c4 = tid & 15, rr = tid >> 4;
  for (int rep = 0; rep < 4; rep++) {
    int r = rr + rep * 16;
    float4 v = *(const float4*)(src + (size_t)(k0 + r) * DDIM + n0 + c4 * 4);
    t[r][c4 * 4 + 0] = v.x; t[r][c4 * 4 + 1] = v.y;
    t[r][c4 * 4 + 2] = v.z; t[r][c4 * 4 + 3] = v.w;
  }
  __syncthreads();
  for (int rep = 0; rep < 4; rep++) {
    int n = rr + rep * 16;
    ushort4 o;
    o.x = (u16)f2bf(t[c4 * 4 + 0][n]); o.y = (u16)f2bf(t[c4 * 4 + 1][n]);
    o.z = (u16)f2bf(t[c4 * 4 + 2][n]); o.w = (u16)f2bf(t[c4 * 4 + 3][n]);
    *(ushort4*)(dst + (size_t)(n0 + n) * DDIM + k0 + c4 * 4) = o;
  }
}

// ---------------- GEMM: tile 128x128, BK=64, K=1024; A[m][k], BT[n][k] bf16 ----------------
template <int MODE>
__global__ __launch_bounds__(256, 2) void k_gemm(const u16* __restrict__ A,
                                                 const u16* __restrict__ BT,
                                                 const float* __restrict__ bias,
                                                 void* __restrict__ O0,
                                                 void* __restrict__ O1,
                                                 void* __restrict__ O2) {
  __shared__ __align__(16) u16 lA[128 * 64];
  __shared__ __align__(16) u16 lB[128 * 64];
  const int tid = threadIdx.x;
  const int l = tid & 63, w = tid >> 6;
  const int wm = w >> 1, wn = w & 1;
  const int m0 = blockIdx.x * 128, n0 = blockIdx.y * 128;
  const int lr = l >> 4, lc = l & 15;

  const int srow = l >> 3;
  const int scol = ((l & 7) ^ srow) * 8;

  f32x4 acc[4][4];
  for (int mi = 0; mi < 4; mi++)
    for (int ni = 0; ni < 4; ni++)
      acc[mi][ni] = f32x4{0.f, 0.f, 0.f, 0.f};

  for (int kk = 0; kk < 16; kk++) {
    const int k0 = kk * 64;
    for (int i = 0; i < 4; i++) {
      int c = w * 4 + i;
      gload16(A + (size_t)(m0 + c * 8 + srow) * DDIM + k0 + scol, (char*)lA + c * 1024);
      gload16(BT + (size_t)(n0 + c * 8 + srow) * DDIM + k0 + scol, (char*)lB + c * 1024);
    }
    __syncthreads();
    for (int ks = 0; ks < 2; ks++) {
      bf16x8 af[4], bfr[4];
      for (int mi = 0; mi < 4; mi++) {
        int row = wm * 64 + mi * 16 + lc;
        int slot = (ks * 4 + lr) ^ (row & 7);
        af[mi] = *(const bf16x8*)((const char*)lA + row * 128 + slot * 16);
      }
      for (int ni = 0; ni < 4; ni++) {
        int row = wn * 64 + ni * 16 + lc;
        int slot = (ks * 4 + lr) ^ (row & 7);
        bfr[ni] = *(const bf16x8*)((const char*)lB + row * 128 + slot * 16);
      }
      for (int mi = 0; mi < 4; mi++)
        for (int ni = 0; ni < 4; ni++)
          acc[mi][ni] = __builtin_amdgcn_mfma_f32_16x16x32_bf16(af[mi], bfr[ni], acc[mi][ni], 0, 0, 0);
    }
    __syncthreads();
  }

  if (MODE == 0) {
    const int which = blockIdx.y >> 3;
    if (which == 0) {
      u16* C = (u16*)O0;
      const float c1 = 0.18033688011112043f;  // 0.125 * log2(e) folded into Q
      for (int mi = 0; mi < 4; mi++)
        for (int ni = 0; ni < 4; ni++) {
          int nl = (n0 + wn * 64 + ni * 16 + lc) & 1023;
          float badd = bias[nl];
          for (int r = 0; r < 4; r++) {
            int m = m0 + wm * 64 + mi * 16 + lr * 4 + r;
            C[(size_t)m * DDIM + nl] = (u16)f2bf((acc[mi][ni][r] + badd) * c1);
          }
        }
    } else if (which == 1) {
      u16* C = (u16*)O1;
      for (int mi = 0; mi < 4; mi++)
        for (int ni = 0; ni < 4; ni++) {
          int nl = (n0 + wn * 64 + ni * 16 + lc) & 1023;
          for (int r = 0; r < 4; r++) {
            int m = m0 + wm * 64 + mi * 16 + lr * 4 + r;
            C[(size_t)m * DDIM + nl] = (u16)f2bf(acc[mi][ni][r]);
          }
        }
    } else {
      u16* C = (u16*)O2;  // [bh][hd][s]
      for (int mi = 0; mi < 4; mi++)
        for (int ni = 0; ni < 4; ni++) {
          int nl = (n0 + wn * 64 + ni * 16 + lc) & 1023;
          int h = nl >> 6, hd = nl & 63;
          int m = m0 + wm * 64 + mi * 16 + lr * 4;
          int b = m >> 11, s = m & 2047;
          unsigned d0 = f2bf(acc[mi][ni][0]) | (f2bf(acc[mi][ni][1]) << 16);
          unsigned d1 = f2bf(acc[mi][ni][2]) | (f2bf(acc[mi][ni][3]) << 16);
          u16* p = C + ((size_t)((b * HH + h) * HDIM + hd)) * SS + s;
          *(unsigned*)(p) = d0;
          *(unsigned*)(p + 2) = d1;
        }
    }
  } else {
    float* C = (float*)O0;
    for (int mi = 0; mi < 4; mi++)
      for (int ni = 0; ni < 4; ni++) {
        int n = n0 + wn * 64 + ni * 16 + lc;
        float badd = bias[n];
        for (int r = 0; r < 4; r++) {
          int m = m0 + wm * 64 + mi * 16 + lr * 4 + r;
          C[(size_t)m * DDIM + n] = acc[mi][ni][r] + badd;
        }
      }
  }
}

// ---------------- flash attention: 32x32 core (R10) in R8 launch geometry ----------
// Block = 128 threads (2 waves), one 64-q tile qt: wave w owns q [qt*64+w*32, +32).
// Both waves run EXACTLY qt+1 periods (even wave skips+masks key-tile 0 on diagonal,
// odd wave masks key-tile 1). In-register softmax, P via cvt_pk+permlane32_swap.
__global__ __launch_bounds__(128, 2) void k_attn(const u16* __restrict__ Q,
                                                 const u16* __restrict__ Kg,
                                                 const u16* __restrict__ Vt,
                                                 u16* __restrict__ AO) {
  __shared__ __align__(16) u16 lK[2][64 * 64];  // [key][d] XOR-swizzled, dbuf (16 KB)
  __shared__ __align__(16) u16 lV[2][64 * 64];  // [hd][key] XOR-swizzled, dbuf (16 KB)

  const int tid = threadIdx.x;
  const int l = tid & 63, w = tid >> 6;          // 2 waves
  const int lq = l & 31, hi = l >> 5;
  // R8-proven dispatch: id%32 = bh (XCD affinity), qt paired {gg, 31-gg}
  const int id = blockIdx.x;
  const int bh = id & 31;
  const int s5 = (id >> 5) & 1;
  const int gg = id >> 6;
  const int qt = s5 ? (31 - gg) : gg;
  const int b = bh >> 4, h = bh & 15;
  const int qglob = qt * 64 + w * 32 + lq;
  const int nkt = qt + 1;                        // same for BOTH waves

  const float slope2 = exp2f(-0.5f * (float)(h + 1)) * 1.4426950408889634f;
  const float sh4 = slope2 * (float)(4 * hi);

  // per-reg ALiBi constants: scr[r] = slope2 * crow(r) (crow = (r&3)+8*(r>>2))
  f32x16 scr;
#pragma unroll
  for (int r = 0; r < 16; r++) scr[r] = slope2 * (float)((r & 3) + 8 * (r >> 2));

  // Q B-frags: col q = lq, k(d) = sd*16 + hi*8 + j
  bf16x8 qf[4];
#pragma unroll
  for (int sd = 0; sd < 4; sd++)
    qf[sd] = *(const bf16x8*)(Q + (size_t)(b * SS + qglob) * DDIM + h * HDIM + sd * 16 + hi * 8);

  f32x16 o0 = zero16(), o1 = zero16();
  float mrun = -3.0e38f, lrl = 0.f;

  const int srow = l >> 3;
  const int scol = ((l & 7) ^ srow) * 8;

  auto stage = [&](int kt, int bb) {
#pragma unroll
    for (int i = 0; i < 4; i++) {
      int c = i * 2 + w;   // 8 chunks each of K and V (8 rows x 64 cols = 1 KB)
      gload16(Kg + (size_t)(b * SS + kt * 64 + c * 8 + srow) * DDIM + h * HDIM + scol,
              (char*)lK[bb] + c * 1024);
      gload16(Vt + ((size_t)bh * HDIM + c * 8 + srow) * SS + kt * 64 + scol,
              (char*)lV[bb] + c * 1024);
    }
  };

  // prologue: two tiles in flight (clamped for nkt==1)
  stage(0, 0);
  stage(nkt > 1 ? 1 : 0, 1);

  for (int t = 0; t < nkt; t++) {
    asm volatile("s_waitcnt vmcnt(8)" ::: "memory");
    __builtin_amdgcn_s_barrier();
    asm volatile("" ::: "memory");
    {
      const char* Kc = (const char*)lK[t & 1];
      const char* Vc = (const char*)lV[t & 1];
      const bool lastp = (t == nkt - 1);
      const bool doT1 = !lastp || (w == 1);   // even wave's last period: skip key-tile 1
      const bool mT0 = lastp && (w == 0);
      const bool mT1 = lastp && (w == 1);

      // S^T[key][q] = K . Q^T  (2 key-tiles x 4 d-steps)
      f32x16 s0 = zero16(), s1 = zero16();
      __builtin_amdgcn_s_setprio(1);
#pragma unroll
      for (int sd = 0; sd < 4; sd++) {
        int row = lq;
        int slot = (2 * sd + hi) ^ (row & 7);
        bf16x8 a = *(const bf16x8*)(Kc + row * 128 + slot * 16);
        s0 = __builtin_amdgcn_mfma_f32_32x32x16_bf16(a, qf[sd], s0, 0, 0, 0);
      }
      if (doT1) {
#pragma unroll
        for (int sd = 0; sd < 4; sd++) {
          int row = 32 + lq;
          int slot = (2 * sd + hi) ^ (row & 7);
          bf16x8 a = *(const bf16x8*)(Kc + row * 128 + slot * 16);
          s1 = __builtin_amdgcn_mfma_f32_32x32x16_bf16(a, qf[sd], s1, 0, 0, 0);
        }
      }
      __builtin_amdgcn_s_setprio(0);

      // ALiBi (exp2 domain) + causal mask + per-lane max over held keys
      const float bt0 = -slope2 * (float)(t * 64) - sh4;
      const float bt1 = bt0 - slope2 * 32.f;
      float tmax = -3.0e38f;
#pragma unroll
      for (int r = 0; r < 16; r++) {
        float sv = (s0[r] + bt0) - scr[r];
        if (mT0) {
          int key = t * 64 + (r & 3) + 8 * (r >> 2) + 4 * hi;
          if (key > qglob) sv = -3.0e38f;
        }
        s0[r] = sv;
        tmax = fmaxf(tmax, sv);
      }
      if (doT1) {
#pragma unroll
        for (int r = 0; r < 16; r++) {
          float sv = (s1[r] + bt1) - scr[r];
          if (mT1) {
            int key = t * 64 + 32 + (r & 3) + 8 * (r >> 2) + 4 * hi;
            if (key > qglob) sv = -3.0e38f;
          }
          s1[r] = sv;
          tmax = fmaxf(tmax, sv);
        }
      }
      // column max: in-lane tree done; ONE cross-lane exchange (partner half)
      float tcol = fmaxf(tmax, __shfl_xor(tmax, 32));
      if (__any(tcol > mrun)) {
        float mnew = fmaxf(mrun, tcol);
        float corr = exp2f(mrun - mnew);
        lrl *= corr;
#pragma unroll
        for (int r = 0; r < 16; r++) { o0[r] *= corr; o1[r] *= corr; }
        mrun = mnew;
      }

      // p = exp2(sv - m): per-lane partial denominator (combined once at epilogue)
      f32x4 ps = f32x4{0.f, 0.f, 0.f, 0.f};
#pragma unroll
      for (int r = 0; r < 16; r++) {
        float p = exp2f(s0[r] - mrun);
        s0[r] = p;
        ps[r & 3] += p;
      }
      if (doT1) {
#pragma unroll
        for (int r = 0; r < 16; r++) {
          float p = exp2f(s1[r] - mrun);
          s1[r] = p;
          ps[r & 3] += p;
        }
      }
      lrl += (ps[0] + ps[1]) + (ps[2] + ps[3]);

      // O^T[hd][q] += V^T . P : P -> B-frags in-register (cvt_pk + permlane32_swap)
      __builtin_amdgcn_s_setprio(1);
      auto pvstep = [&](const f32x16& cs, int s) {  // s = 16-key step 0..3 (unroll const)
        const int b8 = (s & 1) * 8;
        unsigned x1 = cvt_pk_bf16(cs[b8 + 0], cs[b8 + 1]);
        unsigned y1 = cvt_pk_bf16(cs[b8 + 4], cs[b8 + 5]);
        pswap(x1, y1);   // x1 -> keys (0,1)+8hi; y1 -> keys (4,5)+8hi
        unsigned x2 = cvt_pk_bf16(cs[b8 + 2], cs[b8 + 3]);
        unsigned y2 = cvt_pk_bf16(cs[b8 + 6], cs[b8 + 7]);
        pswap(x2, y2);   // x2 -> keys (2,3)+8hi; y2 -> keys (6,7)+8hi
        uint4 pw; pw.x = x1; pw.y = x2; pw.z = y1; pw.w = y2;
        bf16x8 pb = __builtin_bit_cast(bf16x8, pw);
        int slotb = 2 * s + hi;
        {
          int row = lq;
          bf16x8 va = *(const bf16x8*)(Vc + row * 128 + ((slotb ^ (row & 7)) << 4));
          o0 = __builtin_amdgcn_mfma_f32_32x32x16_bf16(va, pb, o0, 0, 0, 0);
        }
        {
          int row = 32 + lq;
          bf16x8 va = *(const bf16x8*)(Vc + row * 128 + ((slotb ^ (row & 7)) << 4));
          o1 = __builtin_amdgcn_mfma_f32_32x32x16_bf16(va, pb, o1, 0, 0, 0);
        }
      };
      pvstep(s0, 0);
      pvstep(s0, 1);
      if (doT1) {
        pvstep(s1, 2);
        pvstep(s1, 3);
      }
      __builtin_amdgcn_s_setprio(0);
    }
    __builtin_amdgcn_s_barrier();
    asm volatile("" ::: "memory");
    int kts = t + 2;
    if (kts > nkt - 1) kts = nkt - 1;   // redundant stage keeps vmcnt counts uniform
    stage(kts, t & 1);
  }

  // epilogue: combine per-lane denominator with partner half; normalize; write O
  float lcol = lrl + __shfl_xor(lrl, 32);
  float inv = 1.f / lcol;
  u16* obase = AO + (size_t)(b * SS + qglob) * DDIM + h * HDIM;
#pragma unroll
  for (int rg = 0; rg < 4; rg++) {
    uint2 uu;
    uu.x = cvt_pk_bf16(o0[4 * rg + 0] * inv, o0[4 * rg + 1] * inv);
    uu.y = cvt_pk_bf16(o0[4 * rg + 2] * inv, o0[4 * rg + 3] * inv);
    *(uint2*)(obase + rg * 8 + 4 * hi) = uu;
    uu.x = cvt_pk_bf16(o1[4 * rg + 0] * inv, o1[4 * rg + 1] * inv);
    uu.y = cvt_pk_bf16(o1[4 * rg + 2] * inv, o1[4 * rg + 3] * inv);
    *(uint2*)(obase + 32 + rg * 8 + 4 * hi) = uu;
  }
}

extern "C" void kernel_launch(void* const* d_in, const int* in_sizes, int n_in,
                              void* d_out, int out_size, void* d_ws, size_t ws_size,
                              hipStream_t stream) {
  const float* x  = (const float*)d_in[0];
  const float* Wq = (const float*)d_in[1];
  const float* bq = (const float*)d_in[2];
  const float* Wk = (const float*)d_in[3];
  const float* Wv = (const float*)d_in[4];
  const float* Wo = (const float*)d_in[5];
  const float* bo = (const float*)d_in[6];
  float* out = (float*)d_out;

  u16* ws = (u16*)d_ws;
  const size_t MEG = 1024 * 1024;
  u16* xb = ws;                  // 4M elems
  u16* WT = ws + 4 * MEG;        // 4 x 1M elems: WqT,WkT,WvT,WoT
  u16* Qb = ws + 8 * MEG;        // 4M
  u16* Kb = ws + 12 * MEG;       // 4M
  u16* Vt = ws + 16 * MEG;       // 4M  [32][64][2048]
  u16* AO = ws + 20 * MEG;       // 4M

  k_convert_x<<<dim3(4096), dim3(256), 0, stream>>>(x, xb);
  k_transpose_w<<<dim3(16, 16, 4), dim3(256), 0, stream>>>(Wq, Wk, Wv, Wo, WT);
  k_gemm<0><<<dim3(32, 24), dim3(256), 0, stream>>>(xb, WT, bq, (void*)Qb, (void*)Kb, (void*)Vt);
  k_attn<<<dim3(1024), dim3(128), 0, stream>>>(Qb, Kb, Vt, AO);
  k_gemm<1><<<dim3(32, 8), dim3(256), 0, stream>>>(AO, WT + 3 * MEG, bo, (void*)out, nullptr, nullptr);
}

// Round 12
// 129.590 us; speedup vs baseline: 1.0310x; 1.0286x over previous
//
#include <hip/hip_runtime.h>
#include <stdint.h>

#define DDIM 1024
#define HH 16
#define HDIM 64
#define SS 2048

typedef short bf16x8 __attribute__((ext_vector_type(8)));
typedef float f32x4 __attribute__((ext_vector_type(4)));
typedef unsigned short u16;

__device__ __forceinline__ unsigned f2bf(float f) {
  unsigned u = __builtin_bit_cast(unsigned, f);
  u = u + 0x7FFFu + ((u >> 16) & 1u);   // RNE (inputs finite)
  return u >> 16;
}

// packs RNE-converted a->lo16, b->hi16
__device__ __forceinline__ unsigned cvt_pk_bf16(float a, float b) {
  unsigned r;
  asm("v_cvt_pk_bf16_f32 %0, %1, %2" : "=v"(r) : "v"(a), "v"(b));
  return r;
}

__device__ __forceinline__ void gload16(const void* g, void* l) {
  __builtin_amdgcn_global_load_lds(
      (const __attribute__((address_space(1))) unsigned int*)g,
      (__attribute__((address_space(3))) unsigned int*)l, 16, 0, 0);
}

// ---------------- convert x: fp32 -> bf16 ----------------
__global__ void k_convert_x(const float* __restrict__ x, u16* __restrict__ xb) {
  int i = (blockIdx.x * 256 + threadIdx.x) * 4;
  float4 v = *(const float4*)(x + i);
  ushort4 o;
  o.x = (u16)f2bf(v.x); o.y = (u16)f2bf(v.y); o.z = (u16)f2bf(v.z); o.w = (u16)f2bf(v.w);
  *(ushort4*)(xb + i) = o;
}

// ---------------- transpose+convert weights: W[k][n] -> WT[n][k] bf16 ----------------
__global__ void k_transpose_w(const float* __restrict__ w0, const float* __restrict__ w1,
                              const float* __restrict__ w2, const float* __restrict__ w3,
                              u16* __restrict__ wt) {
  __shared__ float t[64][65];
  int z = blockIdx.z;
  const float* src = (z == 0) ? w0 : (z == 1) ? w1 : (z == 2) ? w2 : w3;
  u16* dst = wt + (size_t)z * DDIM * DDIM;
  int k0 = blockIdx.x * 64, n0 = blockIdx.y * 64;
  int tid = threadIdx.x;
  int c4 = tid & 15, rr = tid >> 4;
  for (int rep = 0; rep < 4; rep++) {
    int r = rr + rep * 16;
    float4 v = *(const float4*)(src + (size_t)(k0 + r) * DDIM + n0 + c4 * 4);
    t[r][c4 * 4 + 0] = v.x; t[r][c4 * 4 + 1] = v.y;
    t[r][c4 * 4 + 2] = v.z; t[r][c4 * 4 + 3] = v.w;
  }
  __syncthreads();
  for (int rep = 0; rep < 4; rep++) {
    int n = rr + rep * 16;
    ushort4 o;
    o.x = (u16)f2bf(t[c4 * 4 + 0][n]); o.y = (u16)f2bf(t[c4 * 4 + 1][n]);
    o.z = (u16)f2bf(t[c4 * 4 + 2][n]); o.w = (u16)f2bf(t[c4 * 4 + 3][n]);
    *(ushort4*)(dst + (size_t)(n0 + n) * DDIM + k0 + c4 * 4) = o;
  }
}

// ---------------- GEMM: tile 128x128, BK=64, K=1024; A[m][k], BT[n][k] bf16 ----------------
template <int MODE>
__global__ __launch_bounds__(256, 2) void k_gemm(const u16* __restrict__ A,
                                                 const u16* __restrict__ BT,
                                                 const float* __restrict__ bias,
                                                 void* __restrict__ O0,
                                                 void* __restrict__ O1,
                                                 void* __restrict__ O2) {
  __shared__ __align__(16) u16 lA[128 * 64];
  __shared__ __align__(16) u16 lB[128 * 64];
  const int tid = threadIdx.x;
  const int l = tid & 63, w = tid >> 6;
  const int wm = w >> 1, wn = w & 1;
  const int m0 = blockIdx.x * 128, n0 = blockIdx.y * 128;
  const int lr = l >> 4, lc = l & 15;

  const int srow = l >> 3;
  const int scol = ((l & 7) ^ srow) * 8;

  f32x4 acc[4][4];
  for (int mi = 0; mi < 4; mi++)
    for (int ni = 0; ni < 4; ni++)
      acc[mi][ni] = f32x4{0.f, 0.f, 0.f, 0.f};

  for (int kk = 0; kk < 16; kk++) {
    const int k0 = kk * 64;
    for (int i = 0; i < 4; i++) {
      int c = w * 4 + i;
      gload16(A + (size_t)(m0 + c * 8 + srow) * DDIM + k0 + scol, (char*)lA + c * 1024);
      gload16(BT + (size_t)(n0 + c * 8 + srow) * DDIM + k0 + scol, (char*)lB + c * 1024);
    }
    __syncthreads();
    for (int ks = 0; ks < 2; ks++) {
      bf16x8 af[4], bfr[4];
      for (int mi = 0; mi < 4; mi++) {
        int row = wm * 64 + mi * 16 + lc;
        int slot = (ks * 4 + lr) ^ (row & 7);
        af[mi] = *(const bf16x8*)((const char*)lA + row * 128 + slot * 16);
      }
      for (int ni = 0; ni < 4; ni++) {
        int row = wn * 64 + ni * 16 + lc;
        int slot = (ks * 4 + lr) ^ (row & 7);
        bfr[ni] = *(const bf16x8*)((const char*)lB + row * 128 + slot * 16);
      }
      for (int mi = 0; mi < 4; mi++)
        for (int ni = 0; ni < 4; ni++)
          acc[mi][ni] = __builtin_amdgcn_mfma_f32_16x16x32_bf16(af[mi], bfr[ni], acc[mi][ni], 0, 0, 0);
    }
    __syncthreads();
  }

  if (MODE == 0) {
    const int which = blockIdx.y >> 3;
    if (which == 0) {
      u16* C = (u16*)O0;
      const float c1 = 0.18033688011112043f;  // 0.125 * log2(e) folded into Q
      for (int mi = 0; mi < 4; mi++)
        for (int ni = 0; ni < 4; ni++) {
          int nl = (n0 + wn * 64 + ni * 16 + lc) & 1023;
          float badd = bias[nl];
          for (int r = 0; r < 4; r++) {
            int m = m0 + wm * 64 + mi * 16 + lr * 4 + r;
            C[(size_t)m * DDIM + nl] = (u16)f2bf((acc[mi][ni][r] + badd) * c1);
          }
        }
    } else if (which == 1) {
      u16* C = (u16*)O1;
      for (int mi = 0; mi < 4; mi++)
        for (int ni = 0; ni < 4; ni++) {
          int nl = (n0 + wn * 64 + ni * 16 + lc) & 1023;
          for (int r = 0; r < 4; r++) {
            int m = m0 + wm * 64 + mi * 16 + lr * 4 + r;
            C[(size_t)m * DDIM + nl] = (u16)f2bf(acc[mi][ni][r]);
          }
        }
    } else {
      u16* C = (u16*)O2;  // [bh][hd][s]
      for (int mi = 0; mi < 4; mi++)
        for (int ni = 0; ni < 4; ni++) {
          int nl = (n0 + wn * 64 + ni * 16 + lc) & 1023;
          int h = nl >> 6, hd = nl & 63;
          int m = m0 + wm * 64 + mi * 16 + lr * 4;
          int b = m >> 11, s = m & 2047;
          unsigned d0 = f2bf(acc[mi][ni][0]) | (f2bf(acc[mi][ni][1]) << 16);
          unsigned d1 = f2bf(acc[mi][ni][2]) | (f2bf(acc[mi][ni][3]) << 16);
          u16* p = C + ((size_t)((b * HH + h) * HDIM + hd)) * SS + s;
          *(unsigned*)(p) = d0;
          *(unsigned*)(p + 2) = d1;
        }
    }
  } else {
    float* C = (float*)O0;
    for (int mi = 0; mi < 4; mi++)
      for (int ni = 0; ni < 4; ni++) {
        int n = n0 + wn * 64 + ni * 16 + lc;
        float badd = bias[n];
        for (int r = 0; r < 4; r++) {
          int m = m0 + wm * 64 + mi * 16 + lr * 4 + r;
          C[(size_t)m * DDIM + n] = acc[mi][ni][r] + badd;
        }
      }
  }
}

// ---------------- flash attention tile body (R8-proven core, verbatim) ----------------
__device__ __forceinline__ void attn_tile(int kt, bool masked, int kfhi,
                                          const char* lKc, const char* lVc, char* lPw,
                                          const bf16x8 qf[2], f32x4 of[4],
                                          float& mrun, float& lrun_lane,
                                          float slope2, int lr, int lc, int q_glob) {
  // S^T[key][q] = K . Q^T
  f32x4 sf[4];
#pragma unroll
  for (int kf = 0; kf < 4; kf++) sf[kf] = f32x4{0.f, 0.f, 0.f, 0.f};
  __builtin_amdgcn_s_setprio(1);
#pragma unroll
  for (int ks = 0; ks < 2; ks++)
#pragma unroll
    for (int kf = 0; kf < 4; kf++) {
      if (kf >= kfhi) continue;
      int key = kf * 16 + lc;
      int slot = (ks * 4 + lr) ^ (lc & 7);
      bf16x8 a = *(const bf16x8*)(lKc + key * 128 + slot * 16);
      sf[kf] = __builtin_amdgcn_mfma_f32_16x16x32_bf16(a, qf[ks], sf[kf], 0, 0, 0);
    }
  __builtin_amdgcn_s_setprio(0);

  // ALiBi (exp2 domain) + causal mask + per-lane max
  const float base = -slope2 * (float)(kt * 64 + lr * 4);
  float tmax = -3.0e38f;
#pragma unroll
  for (int kf = 0; kf < 4; kf++) {
    if (kf >= kfhi) continue;
#pragma unroll
    for (int r = 0; r < 4; r++) {
      float sv = sf[kf][r] + (base - slope2 * (float)(kf * 16 + r));
      if (masked) {
        int key = kt * 64 + kf * 16 + lr * 4 + r;
        if (key > q_glob) sv = -3.0e38f;
      }
      sf[kf][r] = sv;
      tmax = fmaxf(tmax, sv);
    }
  }

  // defer-max: cross-lane reduce + rescale only if some lane exceeds running max
  if (__any(tmax > mrun)) {
    float tcol = fmaxf(tmax, __shfl_xor(tmax, 16));
    tcol = fmaxf(tcol, __shfl_xor(tcol, 32));
    if (tcol > mrun) {
      float corr = exp2f(mrun - tcol);
      lrun_lane *= corr;
#pragma unroll
      for (int mf = 0; mf < 4; mf++) {
        of[mf][0] *= corr; of[mf][1] *= corr; of[mf][2] *= corr; of[mf][3] *= corr;
      }
      mrun = tcol;
    }
  }

  // p = exp2(sv - m): per-lane partial denominator; packed bf16 P -> per-wave LDS
  const int kfUp = (kfhi + 1) & ~1;
  f32x4 ps = f32x4{0.f, 0.f, 0.f, 0.f};
#pragma unroll
  for (int kf = 0; kf < 4; kf++) {
    if (kf >= kfUp) continue;
    uint2 uu;
    if (kf < kfhi) {
      float p0 = exp2f(sf[kf][0] - mrun);
      float p1 = exp2f(sf[kf][1] - mrun);
      float p2 = exp2f(sf[kf][2] - mrun);
      float p3 = exp2f(sf[kf][3] - mrun);
      ps[0] += p0; ps[1] += p1; ps[2] += p2; ps[3] += p3;
      uu.x = cvt_pk_bf16(p0, p1);
      uu.y = cvt_pk_bf16(p2, p3);
    } else {
      uu.x = 0u; uu.y = 0u;
    }
    int slot = ((kf * 2 + (lr >> 1)) ^ (lc & 7));
    *(uint2*)(lPw + lc * 128 + slot * 16 + (lr & 1) * 8) = uu;
  }
  lrun_lane += (ps[0] + ps[1]) + (ps[2] + ps[3]);

  // O^T[hd][q] += V^T . P  (mfma_16x16x32, b128 reads)
  const int kshi = kfUp >> 1;
  __builtin_amdgcn_s_setprio(1);
#pragma unroll
  for (int ks = 0; ks < 2; ks++) {
    if (ks >= kshi) continue;
    int slotp = (ks * 4 + lr) ^ (lc & 7);
    bf16x8 pb = *(const bf16x8*)(lPw + lc * 128 + slotp * 16);
#pragma unroll
    for (int mf = 0; mf < 4; mf++) {
      int hd = mf * 16 + lc;
      int slotv = (ks * 4 + lr) ^ (lc & 7);
      bf16x8 va = *(const bf16x8*)(lVc + hd * 128 + slotv * 16);
      of[mf] = __builtin_amdgcn_mfma_f32_16x16x32_bf16(va, pb, of[mf], 0, 0, 0);
    }
  }
  __builtin_amdgcn_s_setprio(0);
}

// ---------------- split-K flash attention: block = (bh, qt, key-chunk of <=8 tiles) ----
// 2560 blocks (80 chunks/bh). Writes PARTIAL O (f32, unnormalized) + per-q (m, l).
// Max 8 periods per block -> longest-block critical path cut 4x vs R8.
__global__ __launch_bounds__(256, 4) void k_attn(const u16* __restrict__ Q,
                                                 const u16* __restrict__ Kg,
                                                 const u16* __restrict__ Vt,
                                                 float* __restrict__ Opart,
                                                 float* __restrict__ Ml) {
  __shared__ __align__(16) u16 lK[2][64 * 64];  // [key][hd] XOR-swizzled, dbuf (16 KB)
  __shared__ __align__(16) u16 lV[2][64 * 64];  // [hd][key] XOR-swizzled, dbuf (16 KB)
  __shared__ __align__(16) u16 lP[4][16 * 64];  // per-wave P [q][key], swizzled (8 KB)

  const int tid = threadIdx.x;
  const int l = tid & 63, w = tid >> 6;
  const int lr = l >> 4, lc = l & 15;
  // id = u*32 + bh: bh in low bits (XCD affinity); u enumerates (qt, chunk)
  const int id = blockIdx.x;
  const int bh = id & 31;
  int u = id >> 5;                       // 0..79
  int qt = 0, rem = u;
  while (rem >= (qt >> 3) + 1) { rem -= (qt >> 3) + 1; qt++; }
  const int c = rem;                     // chunk index within qt
  const int b = bh >> 4, h = bh & 15;
  const int t0 = c * 8;
  const int t1 = min(t0 + 8, qt + 1);    // tiles [t0, t1)

  const float slope2 = exp2f(-0.5f * (float)(h + 1)) * 1.4426950408889634f;
  const int q_glob = qt * 64 + w * 16 + lc;

  bf16x8 qf[2];
#pragma unroll
  for (int ks = 0; ks < 2; ks++)
    qf[ks] = *(const bf16x8*)(Q + (size_t)(b * SS + q_glob) * DDIM + h * HDIM + ks * 32 + lr * 8);

  f32x4 of[4];
#pragma unroll
  for (int mf = 0; mf < 4; mf++) of[mf] = f32x4{0.f, 0.f, 0.f, 0.f};
  float mrun = -3.0e38f, lrun_lane = 0.f;

  const int srow = l >> 3;
  const int scol = ((l & 7) ^ srow) * 8;
  char* lPw = (char*)lP[w];

  auto stage = [&](int kt, int bb) {
#pragma unroll
    for (int i = 0; i < 2; i++) {
      int cc = i * 4 + w;   // 8 chunks of 8 rows x 64 cols (1 KB)
      gload16(Kg + (size_t)(b * SS + kt * 64 + cc * 8 + srow) * DDIM + h * HDIM + scol,
              (char*)lK[bb] + cc * 1024);
      gload16(Vt + ((size_t)bh * HDIM + cc * 8 + srow) * SS + kt * 64 + scol,
              (char*)lV[bb] + cc * 1024);
    }
  };

  // prologue: two tiles in flight (clamped when chunk has 1 tile)
  stage(t0, 0);
  stage(t0 + 1 < t1 ? t0 + 1 : t0, 1);

  // counted-vmcnt pipeline (R8-verbatim): vmcnt(4) never drains to 0 mid-loop
  for (int t = t0; t < t1; t++) {
    asm volatile("s_waitcnt vmcnt(4)" ::: "memory");
    __builtin_amdgcn_s_barrier();
    asm volatile("" ::: "memory");
    const bool last = (t == qt);
    attn_tile(t, last, last ? (w + 1) : 4,
              (const char*)lK[t & 1], (const char*)lV[t & 1], lPw,
              qf, of, mrun, lrun_lane, slope2, lr, lc, q_glob);
    __builtin_amdgcn_s_barrier();
    asm volatile("" ::: "memory");
    int kts = t + 2;
    if (kts > t1 - 1) kts = t1 - 1;     // redundant stage keeps vmcnt counts uniform
    stage(kts, t & 1);
  }

  // epilogue: reduce deferred denominator; write f32 partials + (m, l)
  float lrun = lrun_lane;
  lrun += __shfl_xor(lrun, 16);
  lrun += __shfl_xor(lrun, 32);
  float* Op = Opart + (size_t)id * 4096 + (w * 16 + lc) * 64;
#pragma unroll
  for (int mf = 0; mf < 4; mf++) {
    float4 v;
    v.x = of[mf][0]; v.y = of[mf][1]; v.z = of[mf][2]; v.w = of[mf][3];
    *(float4*)(Op + mf * 16 + lr * 4) = v;
  }
  if (lr == 0) {
    float2 mlv; mlv.x = mrun; mlv.y = lrun;
    *(float2*)(Ml + (size_t)id * 128 + (w * 16 + lc) * 2) = mlv;
  }
}

// ---------------- combine partials: one block per (bh, qt) ----------------
__global__ __launch_bounds__(256, 4) void k_combine(const float* __restrict__ Opart,
                                                    const float* __restrict__ Ml,
                                                    u16* __restrict__ AO) {
  const int blk = blockIdx.x;          // 1024 = qt*32 + bh (bh low -> XCD affinity)
  const int bh = blk & 31, qt = blk >> 5;
  const int b = bh >> 4, h = bh & 15;
  const int a = qt >> 3;
  const int nc = a + 1;                                  // chunks for this qt
  const int base = (a + 1) * (4 * a + (qt & 7));         // sum of chunks for qt' < qt
  const int tid = threadIdx.x;
  const int q = tid >> 2, seg = (tid & 3) << 4;          // 64 q x 4 segs of 16 hd

  float m0 = -3.0e38f, m1 = -3.0e38f, m2 = -3.0e38f, m3 = -3.0e38f;
  float l0 = 0.f, l1 = 0.f, l2 = 0.f, l3 = 0.f;
#pragma unroll 4
  for (int cc = 0; cc < 4; cc++) {
    if (cc >= nc) continue;
    int sid = (base + cc) * 32 + bh;
    float2 mlv = *(const float2*)(Ml + (size_t)sid * 128 + q * 2);
    if (cc == 0) { m0 = mlv.x; l0 = mlv.y; }
    else if (cc == 1) { m1 = mlv.x; l1 = mlv.y; }
    else if (cc == 2) { m2 = mlv.x; l2 = mlv.y; }
    else { m3 = mlv.x; l3 = mlv.y; }
  }
  float mstar = fmaxf(fmaxf(m0, m1), fmaxf(m2, m3));
  float s0 = exp2f(m0 - mstar), s1 = exp2f(m1 - mstar);
  float s2 = exp2f(m2 - mstar), s3 = exp2f(m3 - mstar);

  float acc[16];
#pragma unroll
  for (int r = 0; r < 16; r++) acc[r] = 0.f;
  float lstar = 0.f;
#pragma unroll 4
  for (int cc = 0; cc < 4; cc++) {
    if (cc >= nc) continue;
    float sc = (cc == 0) ? s0 : (cc == 1) ? s1 : (cc == 2) ? s2 : s3;
    lstar += ((cc == 0) ? l0 : (cc == 1) ? l1 : (cc == 2) ? l2 : l3) * sc;
    int sid = (base + cc) * 32 + bh;
    const float* Op = Opart + (size_t)sid * 4096 + q * 64 + seg;
#pragma unroll
    for (int r4 = 0; r4 < 4; r4++) {
      float4 v = *(const float4*)(Op + r4 * 4);
      acc[r4 * 4 + 0] += v.x * sc;
      acc[r4 * 4 + 1] += v.y * sc;
      acc[r4 * 4 + 2] += v.z * sc;
      acc[r4 * 4 + 3] += v.w * sc;
    }
  }
  float inv = 1.f / lstar;
  unsigned pk[8];
#pragma unroll
  for (int i = 0; i < 8; i++)
    pk[i] = f2bf(acc[2 * i] * inv) | (f2bf(acc[2 * i + 1] * inv) << 16);
  u16* ab = AO + (size_t)(b * SS + qt * 64 + q) * DDIM + h * HDIM + seg;
  uint4 w0; w0.x = pk[0]; w0.y = pk[1]; w0.z = pk[2]; w0.w = pk[3];
  uint4 w1; w1.x = pk[4]; w1.y = pk[5]; w1.z = pk[6]; w1.w = pk[7];
  *(uint4*)(ab) = w0;
  *(uint4*)(ab + 8) = w1;
}

extern "C" void kernel_launch(void* const* d_in, const int* in_sizes, int n_in,
                              void* d_out, int out_size, void* d_ws, size_t ws_size,
                              hipStream_t stream) {
  const float* x  = (const float*)d_in[0];
  const float* Wq = (const float*)d_in[1];
  const float* bq = (const float*)d_in[2];
  const float* Wk = (const float*)d_in[3];
  const float* Wv = (const float*)d_in[4];
  const float* Wo = (const float*)d_in[5];
  const float* bo = (const float*)d_in[6];
  float* out = (float*)d_out;

  u16* ws = (u16*)d_ws;
  const size_t MEG = 1024 * 1024;
  u16* xb = ws;                  // 4M elems
  u16* WT = ws + 4 * MEG;        // 4 x 1M elems: WqT,WkT,WvT,WoT
  u16* Qb = ws + 8 * MEG;        // 4M
  u16* Kb = ws + 12 * MEG;       // 4M
  u16* Vt = ws + 16 * MEG;       // 4M  [32][64][2048]
  u16* AO = ws + 20 * MEG;       // 4M
  float* Opart = (float*)(ws + 24 * MEG);          // 2560 x 4096 f32 = 41.9 MB
  float* Ml    = Opart + (size_t)2560 * 4096;      // 2560 x 128 f32 = 1.3 MB

  k_convert_x<<<dim3(4096), dim3(256), 0, stream>>>(x, xb);
  k_transpose_w<<<dim3(16, 16, 4), dim3(256), 0, stream>>>(Wq, Wk, Wv, Wo, WT);
  k_gemm<0><<<dim3(32, 24), dim3(256), 0, stream>>>(xb, WT, bq, (void*)Qb, (void*)Kb, (void*)Vt);
  k_attn<<<dim3(2560), dim3(256), 0, stream>>>(Qb, Kb, Vt, Opart, Ml);
  k_combine<<<dim3(1024), dim3(256), 0, stream>>>(Opart, Ml, AO);
  k_gemm<1><<<dim3(32, 8), dim3(256), 0, stream>>>(AO, WT + 3 * MEG, bo, (void*)out, nullptr, nullptr);
}